// Round 1
// baseline (6137.330 us; speedup 1.0000x reference)
//
#include <hip/hip_runtime.h>
#include <hip/hip_bf16.h>
#include <stdint.h>

// Sizes from the reference
#define BS   256
#define T_   128
#define TP   127      // T-1
#define DD   128
#define DT   16
#define DB   32
#define DH   256
#define NH   4
#define DS   64
#define DHN  1024

#define OFFV (256u*127u*64u)   // 2080768, size of each output tensor

typedef __attribute__((ext_vector_type(8))) short short8v;
typedef __attribute__((ext_vector_type(4))) float f32x4;
typedef __attribute__((ext_vector_type(2))) unsigned int uint2v;

__device__ __forceinline__ float bf16lo(unsigned u){ return __uint_as_float(u << 16); }
__device__ __forceinline__ float bf16hi(unsigned u){ return __uint_as_float(u & 0xffff0000u); }
__device__ __forceinline__ unsigned short f2bf(float f){
  unsigned u = __float_as_uint(f);
  u += 0x7fffu + ((u >> 16) & 1u);   // RNE
  return (unsigned short)(u >> 16);
}
__device__ __forceinline__ unsigned pk2(float lo, float hi){
  return (unsigned)f2bf(lo) | ((unsigned)f2bf(hi) << 16);
}
__device__ __forceinline__ float softplus_f(float x){
  return fmaxf(x, 0.f) + log1pf(__expf(-fabsf(x)));
}

// ---------------------------------------------------------------------------
// Kernel 1: pack recurrent weights to bf16, paired along the reduction dim.
// hkp[s2*256+d]  = (hk_w[2s2][d], hk_w[2s2+1][d])
// hvp[s2*1024+j] = (hv_w[2s2][j], hv_w[2s2+1][j])
// mutp/sgtp[J2*64+k] = (w[2J2][k], w[2J2+1][k])
// ---------------------------------------------------------------------------
__global__ __launch_bounds__(256) void pack_w_kernel(
    const float* __restrict__ hk_w, const float* __restrict__ hv_w,
    const float* __restrict__ mut_w, const float* __restrict__ sgt_w,
    unsigned* __restrict__ hkp, unsigned* __restrict__ hvp,
    unsigned* __restrict__ mutp, unsigned* __restrict__ sgtp)
{
  int i = blockIdx.x * 256 + threadIdx.x;
  if (i < 32*256) { int s2 = i >> 8, d = i & 255;
    hkp[i] = pk2(hk_w[(2*s2)*256 + d], hk_w[(2*s2+1)*256 + d]); }
  if (i < 32*1024) { int s2 = i >> 10, j = i & 1023;
    hvp[i] = pk2(hv_w[(2*s2)*1024 + j], hv_w[(2*s2+1)*1024 + j]); }
  if (i < 512*64) { int J2 = i >> 6, k = i & 63;
    mutp[i] = pk2(mut_w[(2*J2)*64 + k], mut_w[(2*J2+1)*64 + k]);
    sgtp[i] = pk2(sgt_w[(2*J2)*64 + k], sgt_w[(2*J2+1)*64 + k]); }
}

// ---------------------------------------------------------------------------
// Kernel 2: projection GEMM (MFMA bf16 16x16x32).
// One block per b.  A = inp[b] = [x[b,1:,:] | a[b,:-1,:]]  (128 x 144, padded
// to 160 with zeros; row 127 zeroed).  B-tiles of 64 cols from [q_w | v_w].
// Q output is repacked to Qp4[b][d4][r=t*4+h] (uint2 = bf16 x4 along d),
// V output to Vws[b][t][j] (dword = 2 bf16 cols).
// ---------------------------------------------------------------------------
#define LDA 168   // padded K stride (elements); 336B rows keep 16B alignment

__global__ __launch_bounds__(256) void proj_kernel(
    const float* __restrict__ x, const float* __restrict__ a,
    const float* __restrict__ q_w, const float* __restrict__ q_b,
    const float* __restrict__ v_w, const float* __restrict__ v_b,
    uint2v* __restrict__ Qp4, unsigned* __restrict__ Vws)
{
  const int b    = blockIdx.x;
  const int tid  = threadIdx.x;
  const int lane = tid & 63;
  const int w    = tid >> 6;

  __shared__ __align__(16) unsigned short A_s[128 * LDA];
  __shared__ __align__(16) unsigned short BC_s[64 * LDA];  // union: B (64x160) / C (128x66)

  // ---- stage A (bf16) ----
  for (int idx = tid; idx < 128 * DD; idx += 256) {
    int t = idx >> 7, k = idx & 127;
    float v = (t < TP) ? x[((size_t)b * T_ + 1 + t) * DD + k] : 0.f;
    A_s[t * LDA + k] = f2bf(v);
  }
  for (int idx = tid; idx < 128 * 40; idx += 256) {     // k = 128..167 (zeros past 143)
    int t = idx / 40, kk = idx % 40;
    float v = (t < TP && kk < DT) ? a[((size_t)b * T_ + t) * DT + kk] : 0.f;
    A_s[t * LDA + 128 + kk] = f2bf(v);
  }
  __syncthreads();

  for (int nt = 0; nt < 32; ++nt) {
    const int n0 = nt * 64;
    const bool isQ = (n0 < DHN);
    const float* wsrc = isQ ? q_w : v_w;
    const float* bias = isQ ? q_b : v_b;
    const int nb = isQ ? n0 : (n0 - DHN);

    // ---- stage B transposed: BC_s[n*LDA + k] = w[k][nb+n] ----
    for (int idx = tid; idx < 160 * 64; idx += 256) {
      int k = idx >> 6, n = idx & 63;
      float v = (k < DD + DT) ? wsrc[(size_t)k * DHN + nb + n] : 0.f;
      BC_s[n * LDA + k] = f2bf(v);
    }
    __syncthreads();

    // ---- MFMA: wave w owns rows [w*32, w*32+32) ----
    f32x4 acc[2][4];
#pragma unroll
    for (int mi = 0; mi < 2; ++mi)
#pragma unroll
      for (int ni = 0; ni < 4; ++ni) { f32x4 zz = {0.f,0.f,0.f,0.f}; acc[mi][ni] = zz; }
    const int mb = w * 32;
#pragma unroll
    for (int kc = 0; kc < 5; ++kc) {
      const int ko = kc * 32 + ((lane >> 4) << 3);
      short8v af[2], bf[4];
#pragma unroll
      for (int mi = 0; mi < 2; ++mi)
        af[mi] = *(const short8v*)&A_s[(mb + mi*16 + (lane & 15)) * LDA + ko];
#pragma unroll
      for (int ni = 0; ni < 4; ++ni)
        bf[ni] = *(const short8v*)&BC_s[(ni*16 + (lane & 15)) * LDA + ko];
#pragma unroll
      for (int mi = 0; mi < 2; ++mi)
#pragma unroll
        for (int ni = 0; ni < 4; ++ni)
          acc[mi][ni] = __builtin_amdgcn_mfma_f32_16x16x32_bf16(af[mi], bf[ni], acc[mi][ni], 0, 0, 0);
    }
    __syncthreads();   // all B reads done; BC_s now reused as C

    // ---- epilogue: bias (+relu for Q), bf16 into C region [t][cl], stride 66 ----
#pragma unroll
    for (int mi = 0; mi < 2; ++mi)
#pragma unroll
      for (int ni = 0; ni < 4; ++ni) {
        int cl = ni*16 + (lane & 15);
        float bb = bias[nb + cl];
#pragma unroll
        for (int q = 0; q < 4; ++q) {
          int t = mb + mi*16 + ((lane >> 4) << 2) + q;
          float vv = acc[mi][ni][q] + bb;
          if (isQ) vv = fmaxf(vv, 0.f);
          BC_s[t * 66 + cl] = f2bf(vv);
        }
      }
    __syncthreads();

    if (isQ) {
      // tile covers d = n0/4 .. +16 -> 4 global d4 groups starting at n0>>4
      for (int idx = tid; idx < 4 * 512; idx += 256) {
        int d4l = idx >> 9, r = idx & 511;
        int t = r >> 2, h = r & 3;
        const unsigned short* cr = &BC_s[t * 66 + d4l * 16 + h];
        uint2v u;
        u.x = (unsigned)cr[0] | ((unsigned)cr[4]  << 16);
        u.y = (unsigned)cr[8] | ((unsigned)cr[12] << 16);
        Qp4[((size_t)b * 64 + (n0 >> 4) + d4l) * 512 + r] = u;
      }
    } else {
      int c0 = (n0 - DHN) >> 1;
      for (int idx = tid; idx < 128 * 32; idx += 256) {
        int t = idx >> 5, c2 = idx & 31;
        const unsigned short* cr = &BC_s[t * 66 + c2 * 2];
        Vws[((size_t)b * 128 + t) * 512 + c0 + c2] = (unsigned)cr[0] | ((unsigned)cr[1] << 16);
      }
    }
    __syncthreads();
  }
}

// ---------------------------------------------------------------------------
// Kernel 3: the full 127-step recurrence.  One block per batch element b,
// 512 threads (8 waves).  No inter-block communication at all.
// ---------------------------------------------------------------------------
__global__ __launch_bounds__(512) void recur_kernel(
    const float* __restrict__ x, const float* __restrict__ bvec,
    const float* __restrict__ m, const float* __restrict__ eps,
    const float* __restrict__ bk_w, const float* __restrict__ bk_b,
    const float* __restrict__ bv_w, const float* __restrict__ bv_b,
    const float* __restrict__ hk_b, const float* __restrict__ hv_b,
    const float* __restrict__ mu1_w, const float* __restrict__ mu1_b,
    const float* __restrict__ sg1_w, const float* __restrict__ sg1_b,
    const float* __restrict__ mut_b, const float* __restrict__ sgt_b,
    const unsigned* __restrict__ hkp, const unsigned* __restrict__ hvp,
    const unsigned* __restrict__ mutp, const unsigned* __restrict__ sgtp,
    const uint2v* __restrict__ Qp4, const unsigned* __restrict__ Vws,
    float* __restrict__ out)
{
  const int b    = blockIdx.x;
  const int tid  = threadIdx.x;
  const int lane = tid & 63;
  const int wv   = tid >> 6;

  __shared__ __align__(16) float key_s[DH];
  __shared__ __align__(16) float sc[512];
  __shared__ __align__(16) float p_s[128 * 4];
  __shared__ __align__(16) float val_s[DHN];
  __shared__ __align__(16) float ht_s[DHN];
  __shared__ __align__(16) float red[2 * 8 * 64];
  __shared__ __align__(16) float z_s[DS];
  __shared__ __align__(16) float xb[DD + DB];
  __shared__ float mask_s[128];
  __shared__ __align__(16) float hkb_s[DH];
  __shared__ __align__(16) float hvb_s[DHN];
  __shared__ float mtb_s[DS], stb_s[DS];

  // ---- preload small constants ----
  if (tid < DD + DB) xb[tid] = (tid < DD) ? x[(size_t)b * T_ * DD + tid] : bvec[b * DB + (tid - DD)];
  if (tid >= 256 && tid < 512) hkb_s[tid - 256] = hk_b[tid - 256];
  for (int i = tid; i < DHN; i += 512) hvb_s[i] = hv_b[i];
  if (tid < DS) { mtb_s[tid] = mut_b[tid]; stb_s[tid] = sgt_b[tid]; }

  // ---- mask[t] = (sum_k m[b,1+t,k]) > 0 ----
  for (int t = wv; t < TP; t += 8) {
    const float* mr = m + ((size_t)b * T_ + 1 + t) * DD;
    float s = mr[lane] + mr[lane + 64];
    for (int o = 1; o < 64; o <<= 1) s += __shfl_xor(s, o);
    if (lane == 0) mask_s[t] = (s > 0.f) ? 1.f : 0.f;
  }
  if (tid == 0) mask_s[127] = 0.f;
  __syncthreads();

  const uint2v*   qp = Qp4 + (size_t)b * 64 * 512 + tid;
  const unsigned* vp = Vws + (size_t)b * 128 * 512 + tid;
  const int h0 = (tid & 1) * 2;

  // ---- shared attention phase: key_s,val_s -> ht_s ----
  auto attn_phase = [&]() {
    // scores: thread r = tid handles (t = r>>2, h = r&3); reduce over 256 d's
    float acc0 = 0.f, acc1 = 0.f;
#pragma unroll 8
    for (int d4 = 0; d4 < 64; ++d4) {
      uint2v q = __builtin_nontemporal_load(qp + (size_t)d4 * 512);
      float4 kk = *(const float4*)&key_s[d4 * 4];
      acc0 = fmaf(bf16lo(q.x), kk.x, acc0);
      acc1 = fmaf(bf16hi(q.x), kk.y, acc1);
      acc0 = fmaf(bf16lo(q.y), kk.z, acc0);
      acc1 = fmaf(bf16hi(q.y), kk.w, acc1);
    }
    {
      int t = tid >> 2;
      float s = acc0 + acc1;
      sc[tid] = (mask_s[t] > 0.f) ? s * 0.0625f : -1e9f;
    }
    __syncthreads();
    // softmax over t per head; waves 0..3, head = wave id
    if (tid < 256) {
      int h = wv, l = lane;
      float v1 = sc[l * 4 + h];
      float v2 = (l + 64 < TP) ? sc[(l + 64) * 4 + h] : -3.0e38f;
      float mm = fmaxf(v1, v2);
      for (int o = 1; o < 64; o <<= 1) mm = fmaxf(mm, __shfl_xor(mm, o));
      float e1 = __expf(v1 - mm);
      float e2 = (l + 64 < TP) ? __expf(v2 - mm) : 0.f;
      float ssum = e1 + e2;
      for (int o = 1; o < 64; o <<= 1) ssum += __shfl_xor(ssum, o);
      float inv = 1.f / ssum;
      p_s[l * 4 + h] = e1 * inv;
      if (l + 64 < TP) p_s[(l + 64) * 4 + h] = e2 * inv;
    }
    __syncthreads();
    // PV: thread owns cols 2*tid, 2*tid+1; reduce over t
    float a0 = 0.f, a1 = 0.f;
#pragma unroll 4
    for (int t2 = 0; t2 < TP; ++t2) {
      unsigned v = __builtin_nontemporal_load(vp + (size_t)t2 * 512);
      float2 pp = *(const float2*)&p_s[t2 * 4 + h0];
      a0 = fmaf(pp.x, bf16lo(v), a0);
      a1 = fmaf(pp.y, bf16hi(v), a1);
    }
    int j = tid * 2;
    ht_s[j]     = fmaxf(0.5f * (a0 + val_s[j]), 0.f);
    ht_s[j + 1] = fmaxf(0.5f * (a1 + val_s[j + 1]), 0.f);
    __syncthreads();
  };

  // ================= step 0 =================
  if (tid < 256) {                       // key1 = relu(xb @ bk_w + bk_b)
    float acc = bk_b[tid];
    for (int s = 0; s < DD + DB; ++s) acc = fmaf(xb[s], bk_w[s * DH + tid], acc);
    key_s[tid] = fmaxf(acc, 0.f);
  } else {                               // val1 = xb @ bv_w + bv_b
    int c = tid - 256;
    float a0 = bv_b[c], a1 = bv_b[c + 256], a2 = bv_b[c + 512], a3 = bv_b[c + 768];
    for (int s = 0; s < DD + DB; ++s) {
      float xs = xb[s];
      const float* r = bv_w + (size_t)s * DHN + c;
      a0 = fmaf(xs, r[0], a0);   a1 = fmaf(xs, r[256], a1);
      a2 = fmaf(xs, r[512], a2); a3 = fmaf(xs, r[768], a3);
    }
    val_s[c] = a0; val_s[c + 256] = a1; val_s[c + 512] = a2; val_s[c + 768] = a3;
  }
  __syncthreads();

  attn_phase();

  {  // mu1 / sg1 (f32 weights, used once)
    int k = tid & 63, g = tid >> 6;
    float am = 0.f, as_ = 0.f;
    for (int jl = 0; jl < 128; ++jl) {
      int j = g * 128 + jl;
      float hj = ht_s[j];
      am  = fmaf(hj, mu1_w[(size_t)j * 64 + k], am);
      as_ = fmaf(hj, sg1_w[(size_t)j * 64 + k], as_);
    }
    red[g * 64 + k] = am; red[512 + g * 64 + k] = as_;
  }
  __syncthreads();
  if (tid < 64) {
    float mu = mu1_b[tid], sl = sg1_b[tid];
    for (int g = 0; g < 8; ++g) { mu += red[g * 64 + tid]; sl += red[512 + g * 64 + tid]; }
    float sg = softplus_f(sl);
    float z  = fmaf(sg, eps[(size_t)b * 64 + tid], mu);
    size_t o0 = ((size_t)b * TP + 0) * 64 + tid;
    out[o0] = z; out[OFFV + o0] = mu; out[2ull * OFFV + o0] = sg;
    z_s[tid] = z;
  }
  __syncthreads();

  // ================= steps 1..126 =================
  for (int st = 1; st < TP; ++st) {
    if (tid < 256) {                     // keyt = relu(z @ hk_w + hk_b)
      float acc = hkb_s[tid];
#pragma unroll 8
      for (int s2 = 0; s2 < 32; ++s2) {
        unsigned wq = hkp[s2 * 256 + tid];
        float2 zz = *(const float2*)&z_s[s2 * 2];
        acc = fmaf(zz.x, bf16lo(wq), acc);
        acc = fmaf(zz.y, bf16hi(wq), acc);
      }
      key_s[tid] = fmaxf(acc, 0.f);
    } else {                             // valt = z @ hv_w + hv_b
      int c = tid - 256;
      float a0 = hvb_s[c], a1 = hvb_s[c + 256], a2 = hvb_s[c + 512], a3 = hvb_s[c + 768];
#pragma unroll 4
      for (int s2 = 0; s2 < 32; ++s2) {
        float2 zz = *(const float2*)&z_s[s2 * 2];
        unsigned w0 = hvp[s2 * 1024 + c];
        unsigned w1 = hvp[s2 * 1024 + c + 256];
        unsigned w2 = hvp[s2 * 1024 + c + 512];
        unsigned w3 = hvp[s2 * 1024 + c + 768];
        a0 = fmaf(zz.x, bf16lo(w0), a0); a0 = fmaf(zz.y, bf16hi(w0), a0);
        a1 = fmaf(zz.x, bf16lo(w1), a1); a1 = fmaf(zz.y, bf16hi(w1), a1);
        a2 = fmaf(zz.x, bf16lo(w2), a2); a2 = fmaf(zz.y, bf16hi(w2), a2);
        a3 = fmaf(zz.x, bf16lo(w3), a3); a3 = fmaf(zz.y, bf16hi(w3), a3);
      }
      val_s[c] = a0; val_s[c + 256] = a1; val_s[c + 512] = a2; val_s[c + 768] = a3;
    }
    __syncthreads();

    attn_phase();

    {  // mu / sg via packed bf16 weights
      int k = tid & 63, g = tid >> 6;
      float am0 = 0.f, am1 = 0.f, as0 = 0.f, as1 = 0.f;
#pragma unroll 4
      for (int j2 = 0; j2 < 64; ++j2) {
        int J2 = g * 64 + j2;
        float2 hh = *(const float2*)&ht_s[J2 * 2];
        unsigned wm = mutp[J2 * 64 + k];
        unsigned ws = sgtp[J2 * 64 + k];
        am0 = fmaf(hh.x, bf16lo(wm), am0);
        am1 = fmaf(hh.y, bf16hi(wm), am1);
        as0 = fmaf(hh.x, bf16lo(ws), as0);
        as1 = fmaf(hh.y, bf16hi(ws), as1);
      }
      red[g * 64 + k] = am0 + am1; red[512 + g * 64 + k] = as0 + as1;
    }
    __syncthreads();
    if (tid < 64) {
      float mu = mtb_s[tid], sl = stb_s[tid];
      for (int g = 0; g < 8; ++g) { mu += red[g * 64 + tid]; sl += red[512 + g * 64 + tid]; }
      float sg = softplus_f(sl);
      float z  = fmaf(sg, eps[((size_t)st * BS + b) * 64 + tid], mu);
      size_t o0 = ((size_t)b * TP + st) * 64 + tid;
      out[o0] = z; out[OFFV + o0] = mu; out[2ull * OFFV + o0] = sg;
      z_s[tid] = z;
    }
    __syncthreads();
  }
}

// ---------------------------------------------------------------------------
extern "C" void kernel_launch(void* const* d_in, const int* in_sizes, int n_in,
                              void* d_out, int out_size, void* d_ws, size_t ws_size,
                              hipStream_t stream) {
  const float* x    = (const float*)d_in[0];
  const float* a    = (const float*)d_in[1];
  const float* m    = (const float*)d_in[2];
  const float* bvec = (const float*)d_in[3];
  const float* eps  = (const float*)d_in[4];
  const float* bk_w = (const float*)d_in[5];
  const float* bk_b = (const float*)d_in[6];
  const float* bv_w = (const float*)d_in[7];
  const float* bv_b = (const float*)d_in[8];
  const float* q_w  = (const float*)d_in[9];
  const float* q_b  = (const float*)d_in[10];
  const float* v_w  = (const float*)d_in[11];
  const float* v_b  = (const float*)d_in[12];
  const float* hk_w = (const float*)d_in[13];
  const float* hk_b = (const float*)d_in[14];
  const float* hv_w = (const float*)d_in[15];
  const float* hv_b = (const float*)d_in[16];
  const float* mu1_w= (const float*)d_in[17];
  const float* mu1_b= (const float*)d_in[18];
  const float* sg1_w= (const float*)d_in[19];
  const float* sg1_b= (const float*)d_in[20];
  const float* mut_w= (const float*)d_in[21];
  const float* mut_b= (const float*)d_in[22];
  const float* sgt_w= (const float*)d_in[23];
  const float* sgt_b= (const float*)d_in[24];

  // workspace layout: Qp4 64MB | Vws 64MB | packed weights ~416KB
  char* ws = (char*)d_ws;
  uint2v*   Qp4  = (uint2v*)ws;
  unsigned* Vws  = (unsigned*)(ws + (64ull << 20));
  unsigned* hkp  = (unsigned*)(ws + (128ull << 20));
  unsigned* hvp  = hkp + 32 * 256;
  unsigned* mutp = hvp + 32 * 1024;
  unsigned* sgtp = mutp + 512 * 64;

  pack_w_kernel<<<dim3(128), dim3(256), 0, stream>>>(hk_w, hv_w, mut_w, sgt_w,
                                                     hkp, hvp, mutp, sgtp);
  proj_kernel<<<dim3(256), dim3(256), 0, stream>>>(x, a, q_w, q_b, v_w, v_b, Qp4, Vws);
  recur_kernel<<<dim3(256), dim3(512), 0, stream>>>(x, bvec, m, eps,
      bk_w, bk_b, bv_w, bv_b, hk_b, hv_b,
      mu1_w, mu1_b, sg1_w, sg1_b, mut_b, sgt_b,
      hkp, hvp, mutp, sgtp, Qp4, Vws, (float*)d_out);
}